// Round 1
// baseline (130.805 us; speedup 1.0000x reference)
//
#include <hip/hip_runtime.h>
#include <stdint.h>

#define N_ATOMS   2048
#define NREP      27
#define NCAND     (NREP * N_ATOMS)      // 55296
#define KNN       12
#define CAP       128
#define NEDGE     (N_ATOMS * KNN)       // 24576
// d_out float layout (flat, return order):
#define OFF_EDGE  0                      // 3*NEDGE = 73728
#define OFF_DIST  (3 * NEDGE)            // 73728
#define OFF_SRC   (OFF_DIST + NEDGE)     // 98304
#define OFF_DST   (OFF_SRC + NEDGE)      // 122880
#define OFF_NUM   (OFF_DST + NEDGE)      // 147456

// ---------------------------------------------------------------------------
// Prep: per candidate m = j*2048 + i, compute pos_sc and validity-folded |p|^2
// ws[m] = float4{ px, py, pz, valid ? p.p : 1e32f }
// Also copies `numbers` into the output tail.
// ---------------------------------------------------------------------------
__global__ __launch_bounds__(256) void prep_kernel(
    const float* __restrict__ pos, const float* __restrict__ cell,
    const int* __restrict__ numbers, float4* __restrict__ ws,
    float* __restrict__ out)
{
    int m = blockIdx.x * 256 + threadIdx.x;
    if (m >= NCAND) return;

    float c[9];
#pragma unroll
    for (int q = 0; q < 9; ++q) c[q] = cell[q];

    // inverse via adjugate in double, rounded to f32 (ref: jnp.linalg.inv f32)
    double a00 = c[0], a01 = c[1], a02 = c[2];
    double a10 = c[3], a11 = c[4], a12 = c[5];
    double a20 = c[6], a21 = c[7], a22 = c[8];
    double det = a00 * (a11 * a22 - a12 * a21)
               - a01 * (a10 * a22 - a12 * a20)
               + a02 * (a10 * a21 - a11 * a20);
    double id = 1.0 / det;
    float M[9];  // M[r*3+d] = inv(cell)[r][d]; frac_d = sum_r p_r * M[r*3+d]
    M[0] = (float)(( a11 * a22 - a12 * a21) * id);
    M[1] = (float)((-(a01 * a22 - a02 * a21)) * id);
    M[2] = (float)(( a01 * a12 - a02 * a11) * id);
    M[3] = (float)((-(a10 * a22 - a12 * a20)) * id);
    M[4] = (float)(( a00 * a22 - a02 * a20) * id);
    M[5] = (float)((-(a00 * a12 - a02 * a10)) * id);
    M[6] = (float)(( a10 * a21 - a11 * a20) * id);
    M[7] = (float)((-(a00 * a21 - a01 * a20)) * id);
    M[8] = (float)(( a00 * a11 - a01 * a10) * id);

    int j = m >> 11, i = m & (N_ATOMS - 1);
    float o0 = (float)(j / 9 - 1);
    float o1 = (float)((j / 3) % 3 - 1);
    float o2 = (float)(j % 3 - 1);
    // shift = offs @ cell, contraction order k = 0,1,2 (products exact: o in {-1,0,1})
    float sx = __fadd_rn(__fadd_rn(__fmul_rn(o0, c[0]), __fmul_rn(o1, c[3])), __fmul_rn(o2, c[6]));
    float sy = __fadd_rn(__fadd_rn(__fmul_rn(o0, c[1]), __fmul_rn(o1, c[4])), __fmul_rn(o2, c[7]));
    float sz = __fadd_rn(__fadd_rn(__fmul_rn(o0, c[2]), __fmul_rn(o1, c[5])), __fmul_rn(o2, c[8]));
    float px = __fadd_rn(pos[i * 3 + 0], sx);
    float py = __fadd_rn(pos[i * 3 + 1], sy);
    float pz = __fadd_rn(pos[i * 3 + 2], sz);

    // validity: frac in [-eps, 1+eps] per dim, eps = 0.1*min(rownorm)/rownorm
    float rn[3];
#pragma unroll
    for (int r = 0; r < 3; ++r)
        rn[r] = sqrtf(c[r*3]*c[r*3] + c[r*3+1]*c[r*3+1] + c[r*3+2]*c[r*3+2]);
    float dx = 0.1f * fminf(rn[0], fminf(rn[1], rn[2]));
    bool valid = true;
#pragma unroll
    for (int d = 0; d < 3; ++d) {
        float f = __fmaf_rn(pz, M[6 + d], __fmaf_rn(py, M[3 + d], __fmul_rn(px, M[d])));
        float eps = dx / rn[d];
        valid = valid && (f >= -eps) && (f <= 1.0f + eps);
    }
    float pp = __fadd_rn(__fadd_rn(__fmul_rn(px, px), __fmul_rn(py, py)), __fmul_rn(pz, pz));
    ws[m] = make_float4(px, py, pz, valid ? pp : 1e32f);

    if (m < N_ATOMS) out[OFF_NUM + m] = (float)numbers[m];
}

// ---------------------------------------------------------------------------
// Main: one block per center atom. Threshold-filter into LDS, then wave-0
// extracts exact top-12 via shfl-min rounds on packed (d2_bits<<32)|idx keys.
// ---------------------------------------------------------------------------
__global__ __launch_bounds__(256) void knn_kernel(
    const float* __restrict__ pos, const float* __restrict__ cell,
    const float4* __restrict__ ws, float* __restrict__ out)
{
    __shared__ unsigned long long sh_keys[CAP];
    __shared__ int sh_cnt;

    const int a = blockIdx.x;
    const int tid = threadIdx.x;

    const float cx = pos[a * 3 + 0];
    const float cy = pos[a * 3 + 1];
    const float cz = pos[a * 3 + 2];
    const float cc = __fadd_rn(__fadd_rn(__fmul_rn(cx, cx), __fmul_rn(cy, cy)), __fmul_rn(cz, cz));

    // initial threshold from density: expected ~32 candidates inside
    float c0 = cell[0], c1 = cell[1], c2 = cell[2],
          c3 = cell[3], c4 = cell[4], c5 = cell[5],
          c6 = cell[6], c7 = cell[7], c8 = cell[8];
    float vol = fabsf(c0 * (c4 * c8 - c5 * c7) - c1 * (c3 * c8 - c5 * c6) + c2 * (c3 * c7 - c4 * c6));
    float T = powf(3.0f * 32.0f * vol / (4.0f * 3.14159265f * (float)N_ATOMS), 2.0f / 3.0f);

    const int self_m = 13 * N_ATOMS + a;
    int cnt = 0;

    for (int att = 0; att < 16; ++att) {
        if (tid == 0) sh_cnt = 0;
        __syncthreads();
#pragma unroll 4
        for (int ch = 0; ch < NCAND / 256; ++ch) {
            int m = ch * 256 + tid;
            float4 p = ws[m];
            float dot = __fmaf_rn(cz, p.z, __fmaf_rn(cy, p.y, __fmul_rn(cx, p.x)));
            float d2 = __fsub_rn(__fadd_rn(cc, p.w), __fmul_rn(2.0f, dot));
            if (d2 < T && m != self_m) {
                int slot = atomicAdd(&sh_cnt, 1);
                if (slot < CAP)
                    sh_keys[slot] = ((unsigned long long)__float_as_uint(d2) << 32) | (unsigned)m;
            }
        }
        __syncthreads();
        cnt = sh_cnt;
        __syncthreads();  // protect sh_cnt read vs next-iter reset
        if (cnt >= KNN && cnt <= CAP) break;
        T = (cnt < KNN) ? T * 2.0f : T * 0.5f;
    }

    // exact top-12 extraction by wave 0 (keys unique -> unique winner each round)
    if (tid < 64) {
        const unsigned long long MAXK = ~0ull;
        unsigned long long k0 = (tid < cnt) ? sh_keys[tid] : MAXK;
        unsigned long long k1 = (tid + 64 < cnt) ? sh_keys[tid + 64] : MAXK;
        unsigned long long lo = (k0 < k1) ? k0 : k1;
        unsigned long long hi = (k0 < k1) ? k1 : k0;
#pragma unroll
        for (int r = 0; r < KNN; ++r) {
            unsigned long long mn = lo;
#pragma unroll
            for (int off = 32; off; off >>= 1) {
                unsigned long long o = __shfl_xor(mn, off, 64);
                mn = (o < mn) ? o : mn;
            }
            if (lo == mn) { lo = hi; hi = MAXK; }  // consume winner
            if (tid == r) {
                unsigned mm = (unsigned)(mn & 0xffffffffu);
                float d2 = __uint_as_float((unsigned)(mn >> 32));
                float4 p = ws[mm];
                int e = a * KNN + r;
                out[OFF_EDGE + 3 * e + 0] = __fsub_rn(p.x, cx);
                out[OFF_EDGE + 3 * e + 1] = __fsub_rn(p.y, cy);
                out[OFF_EDGE + 3 * e + 2] = __fsub_rn(p.z, cz);
                out[OFF_DIST + e] = sqrtf(fmaxf(d2, 0.0f));
                out[OFF_SRC + e]  = (float)(mm & (N_ATOMS - 1));
                out[OFF_DST + e]  = (float)a;
            }
        }
    }
}

extern "C" void kernel_launch(void* const* d_in, const int* in_sizes, int n_in,
                              void* d_out, int out_size, void* d_ws, size_t ws_size,
                              hipStream_t stream) {
    const float* pos     = (const float*)d_in[0];
    const float* cell    = (const float*)d_in[1];
    const int*   numbers = (const int*)d_in[2];
    float*       out     = (float*)d_out;
    float4*      ws      = (float4*)d_ws;   // needs 55296*16 = 884736 B

    hipLaunchKernelGGL(prep_kernel, dim3((NCAND + 255) / 256), dim3(256), 0, stream,
                       pos, cell, numbers, ws, out);
    hipLaunchKernelGGL(knn_kernel, dim3(N_ATOMS), dim3(256), 0, stream,
                       pos, cell, ws, out);
}

// Round 2
// 80.652 us; speedup vs baseline: 1.6218x; 1.6218x over previous
//
#include <hip/hip_runtime.h>
#include <stdint.h>

#define N_ATOMS   2048
#define NREP      27
#define NCAND     (NREP * N_ATOMS)      // 55296
#define KNN       12
#define CAP       128                    // LDS threshold-filter capacity
#define CAPC      8192                   // compacted candidate capacity
#define NEDGE     (N_ATOMS * KNN)        // 24576
// d_out float layout (flat, return order):
#define OFF_EDGE  0                      // 3*NEDGE
#define OFF_DIST  (3 * NEDGE)
#define OFF_SRC   (OFF_DIST + NEDGE)
#define OFF_DST   (OFF_SRC + NEDGE)
#define OFF_NUM   (OFF_DST + NEDGE)
// d_ws layout (bytes):
//   [0..4)    u32 valid-candidate counter (zeroed via hipMemsetAsync)
//   [4..8)    float threshold T (written by prep thread m==0)
//   [256 .. 256+CAPC*16)        float4 cand[CAPC]  {x,y,z,pp}
//   [256+CAPC*16 .. +CAPC*4)    u32    cidx[CAPC]  original m
#define WS_CAND_OFF 256
#define WS_IDX_OFF  (WS_CAND_OFF + CAPC * 16)

// ---------------------------------------------------------------------------
// Prep: compute pos_sc + validity per candidate m = j*2048 + i; compact the
// valid ones (~3.5k of 55k) into a dense array via wave-ballot + global atomic.
// Also writes threshold T, and the `numbers` tail of d_out.
// ---------------------------------------------------------------------------
__global__ __launch_bounds__(256) void prep_kernel(
    const float* __restrict__ pos, const float* __restrict__ cell,
    const int* __restrict__ numbers, unsigned* __restrict__ hdr,
    float4* __restrict__ cand, unsigned* __restrict__ cidx,
    float* __restrict__ out)
{
    int m = blockIdx.x * 256 + threadIdx.x;   // grid is exactly NCAND threads

    float c[9];
#pragma unroll
    for (int q = 0; q < 9; ++q) c[q] = cell[q];

    // inverse via adjugate in double, rounded to f32 (ref: jnp.linalg.inv f32)
    double a00 = c[0], a01 = c[1], a02 = c[2];
    double a10 = c[3], a11 = c[4], a12 = c[5];
    double a20 = c[6], a21 = c[7], a22 = c[8];
    double det = a00 * (a11 * a22 - a12 * a21)
               - a01 * (a10 * a22 - a12 * a20)
               + a02 * (a10 * a21 - a11 * a20);
    double id = 1.0 / det;
    float M[9];  // M[r*3+d] = inv(cell)[r][d]
    M[0] = (float)(( a11 * a22 - a12 * a21) * id);
    M[1] = (float)((-(a01 * a22 - a02 * a21)) * id);
    M[2] = (float)(( a01 * a12 - a02 * a11) * id);
    M[3] = (float)((-(a10 * a22 - a12 * a20)) * id);
    M[4] = (float)(( a00 * a22 - a02 * a20) * id);
    M[5] = (float)((-(a00 * a12 - a02 * a10)) * id);
    M[6] = (float)(( a10 * a21 - a11 * a20) * id);
    M[7] = (float)((-(a00 * a21 - a01 * a20)) * id);
    M[8] = (float)(( a00 * a11 - a01 * a10) * id);

    int j = m >> 11, i = m & (N_ATOMS - 1);
    float o0 = (float)(j / 9 - 1);
    float o1 = (float)((j / 3) % 3 - 1);
    float o2 = (float)(j % 3 - 1);
    float sx = __fadd_rn(__fadd_rn(__fmul_rn(o0, c[0]), __fmul_rn(o1, c[3])), __fmul_rn(o2, c[6]));
    float sy = __fadd_rn(__fadd_rn(__fmul_rn(o0, c[1]), __fmul_rn(o1, c[4])), __fmul_rn(o2, c[7]));
    float sz = __fadd_rn(__fadd_rn(__fmul_rn(o0, c[2]), __fmul_rn(o1, c[5])), __fmul_rn(o2, c[8]));
    float px = __fadd_rn(pos[i * 3 + 0], sx);
    float py = __fadd_rn(pos[i * 3 + 1], sy);
    float pz = __fadd_rn(pos[i * 3 + 2], sz);

    float rn[3];
#pragma unroll
    for (int r = 0; r < 3; ++r)
        rn[r] = sqrtf(c[r*3]*c[r*3] + c[r*3+1]*c[r*3+1] + c[r*3+2]*c[r*3+2]);
    float dx = 0.1f * fminf(rn[0], fminf(rn[1], rn[2]));
    bool valid = true;
#pragma unroll
    for (int d = 0; d < 3; ++d) {
        float f = __fmaf_rn(pz, M[6 + d], __fmaf_rn(py, M[3 + d], __fmul_rn(px, M[d])));
        float eps = dx / rn[d];
        valid = valid && (f >= -eps) && (f <= 1.0f + eps);
    }

    // wave-level compaction: one global atomic per wave
    unsigned long long ball = __ballot(valid);
    int lane = threadIdx.x & 63;
    int nv = __popcll(ball);
    unsigned base = 0;
    if (lane == 0 && nv) base = atomicAdd(hdr, (unsigned)nv);
    base = __shfl(base, 0, 64);
    if (valid) {
        unsigned s = base + __popcll(ball & ((1ull << lane) - 1ull));
        if (s < CAPC) {
            float pp = __fadd_rn(__fadd_rn(__fmul_rn(px, px), __fmul_rn(py, py)), __fmul_rn(pz, pz));
            cand[s] = make_float4(px, py, pz, pp);
            cidx[s] = (unsigned)m;
        }
    }

    if (m == 0) {
        // threshold sized for ~48 expected atoms in sphere (retry is ~never hit)
        float vol = (float)fabs(det);
        float T = powf(3.0f * 48.0f * vol / (4.0f * 3.14159265f * (float)N_ATOMS), 2.0f / 3.0f);
        ((float*)hdr)[1] = T;
    }
    if (m < N_ATOMS) out[OFF_NUM + m] = (float)numbers[m];
}

// ---------------------------------------------------------------------------
// Main: one block per center atom; scan only the compacted valid candidates,
// threshold-filter into LDS, wave 0 extracts exact top-12 via shfl-min rounds
// on packed (d2_bits<<32)|orig_m keys (matches lax.top_k tie-break).
// ---------------------------------------------------------------------------
__global__ __launch_bounds__(256) void knn_kernel(
    const float* __restrict__ pos, const float* __restrict__ cell,
    const unsigned* __restrict__ hdr, const float4* __restrict__ cand,
    const unsigned* __restrict__ cidx, float* __restrict__ out)
{
    __shared__ unsigned long long sh_keys[CAP];
    __shared__ int sh_cnt;

    const int a = blockIdx.x;
    const int tid = threadIdx.x;

    float c[9];
#pragma unroll
    for (int q = 0; q < 9; ++q) c[q] = cell[q];

    const float cx = pos[a * 3 + 0];
    const float cy = pos[a * 3 + 1];
    const float cz = pos[a * 3 + 2];
    const float cc = __fadd_rn(__fadd_rn(__fmul_rn(cx, cx), __fmul_rn(cy, cy)), __fmul_rn(cz, cz));

    const int cnt_c = min((int)hdr[0], CAPC);
    float T = ((const float*)hdr)[1];
    const int self_m = 13 * N_ATOMS + a;
    int cnt = 0;

    for (int att = 0; att < 16; ++att) {
        if (tid == 0) sh_cnt = 0;
        __syncthreads();
        for (int i = tid; i < cnt_c; i += 256) {
            float4 p = cand[i];
            float dot = __fmaf_rn(cz, p.z, __fmaf_rn(cy, p.y, __fmul_rn(cx, p.x)));
            float d2 = __fsub_rn(__fadd_rn(cc, p.w), __fmul_rn(2.0f, dot));
            if (d2 < T) {
                unsigned mi = cidx[i];
                if ((int)mi != self_m) {
                    int slot = atomicAdd(&sh_cnt, 1);
                    if (slot < CAP)
                        sh_keys[slot] = ((unsigned long long)__float_as_uint(d2) << 32) | mi;
                }
            }
        }
        __syncthreads();
        cnt = sh_cnt;
        __syncthreads();  // protect sh_cnt vs next-iter reset
        if (cnt >= KNN && cnt <= CAP) break;
        T = (cnt < KNN) ? T * 2.0f : T * 0.5f;
    }

    if (tid < 64) {
        const unsigned long long MAXK = ~0ull;
        unsigned long long k0 = (tid < cnt) ? sh_keys[tid] : MAXK;
        unsigned long long k1 = (tid + 64 < cnt) ? sh_keys[tid + 64] : MAXK;
        unsigned long long lo = (k0 < k1) ? k0 : k1;
        unsigned long long hi = (k0 < k1) ? k1 : k0;
#pragma unroll
        for (int r = 0; r < KNN; ++r) {
            unsigned long long mn = lo;
#pragma unroll
            for (int off = 32; off; off >>= 1) {
                unsigned long long o = __shfl_xor(mn, off, 64);
                mn = (o < mn) ? o : mn;
            }
            if (lo == mn) { lo = hi; hi = MAXK; }  // consume winner
            if (tid == r) {
                unsigned mm = (unsigned)(mn & 0xffffffffu);
                float d2 = __uint_as_float((unsigned)(mn >> 32));
                // recompute winner position with bit-identical chains as prep
                int jj = (int)(mm >> 11), ii = (int)(mm & (N_ATOMS - 1));
                float o0 = (float)(jj / 9 - 1);
                float o1 = (float)((jj / 3) % 3 - 1);
                float o2 = (float)(jj % 3 - 1);
                float sx = __fadd_rn(__fadd_rn(__fmul_rn(o0, c[0]), __fmul_rn(o1, c[3])), __fmul_rn(o2, c[6]));
                float sy = __fadd_rn(__fadd_rn(__fmul_rn(o0, c[1]), __fmul_rn(o1, c[4])), __fmul_rn(o2, c[7]));
                float sz = __fadd_rn(__fadd_rn(__fmul_rn(o0, c[2]), __fmul_rn(o1, c[5])), __fmul_rn(o2, c[8]));
                float px = __fadd_rn(pos[ii * 3 + 0], sx);
                float py = __fadd_rn(pos[ii * 3 + 1], sy);
                float pz = __fadd_rn(pos[ii * 3 + 2], sz);
                int e = a * KNN + r;
                out[OFF_EDGE + 3 * e + 0] = __fsub_rn(px, cx);
                out[OFF_EDGE + 3 * e + 1] = __fsub_rn(py, cy);
                out[OFF_EDGE + 3 * e + 2] = __fsub_rn(pz, cz);
                out[OFF_DIST + e] = sqrtf(fmaxf(d2, 0.0f));
                out[OFF_SRC + e]  = (float)(mm & (N_ATOMS - 1));
                out[OFF_DST + e]  = (float)a;
            }
        }
    }
}

extern "C" void kernel_launch(void* const* d_in, const int* in_sizes, int n_in,
                              void* d_out, int out_size, void* d_ws, size_t ws_size,
                              hipStream_t stream) {
    const float* pos     = (const float*)d_in[0];
    const float* cell    = (const float*)d_in[1];
    const int*   numbers = (const int*)d_in[2];
    float*       out     = (float*)d_out;

    unsigned* hdr  = (unsigned*)d_ws;
    float4*   cand = (float4*)((char*)d_ws + WS_CAND_OFF);
    unsigned* cidx = (unsigned*)((char*)d_ws + WS_IDX_OFF);

    hipMemsetAsync(d_ws, 0, 4, stream);  // zero valid-candidate counter

    hipLaunchKernelGGL(prep_kernel, dim3(NCAND / 256), dim3(256), 0, stream,
                       pos, cell, numbers, hdr, cand, cidx, out);
    hipLaunchKernelGGL(knn_kernel, dim3(N_ATOMS), dim3(256), 0, stream,
                       pos, cell, hdr, cand, cidx, out);
}